// Round 11
// baseline (348.721 us; speedup 1.0000x reference)
//
#include <hip/hip_runtime.h>

// SlidingWindowAttention: S=512, L=2048, WINDOW=64, STRIDE=32 -> NW=63, E=64, H=8, HD=8
// R11: (1) __launch_bounds__(512,4) on swa_attn. Evidence: occupancy 21% == 1 block/CU
// at (512,2) though LDS permits 2 -- the allocator treats min-waves as TARGET and takes
// up to 256 regs/wave (R9/R10); R8 proved (512,4) -> 64 VGPR, NO spill, 34% occ on a
// heavier body. Live set here ~100 <= 128. Tripwire: WRITE_SIZE > 90MB = spill, revert.
// (2) PV via mfma_f32_16x16x32_f16 (4 MFMA/head vs 8, dense K=32 over keys; V^T reads
// become 16B b128). Enabled by permuting QK A-rows (lane reads K row 8*(ml>>2)+(ml&3))
// so C row r <-> key 8*quad+reg, making exp'd P exactly the x32 B-frag (k=8*quad+idx;
// same mapping the working proj x32 fragments use). proj kernel unchanged from R10.
#define S_DIM 512
#define L_DIM 2048
#define NW 63
#define E_DIM 64

typedef __bf16 bf16_t;
typedef __bf16 bf16x8 __attribute__((ext_vector_type(8)));
typedef float f32x4 __attribute__((ext_vector_type(4)));
typedef _Float16 f16_t;
typedef _Float16 f16x2 __attribute__((ext_vector_type(2)));
typedef _Float16 f16x4 __attribute__((ext_vector_type(4)));
typedef _Float16 f16x8 __attribute__((ext_vector_type(8)));

// 8 consecutive f32 -> bf16x8 MFMA fragment
__device__ inline bf16x8 cvt8(const float* __restrict__ p) {
    float4 a = *(const float4*)p;
    float4 b = *(const float4*)(p + 4);
    bf16x8 r;
    r[0] = (bf16_t)a.x; r[1] = (bf16_t)a.y; r[2] = (bf16_t)a.z; r[3] = (bf16_t)a.w;
    r[4] = (bf16_t)b.x; r[5] = (bf16_t)b.y; r[6] = (bf16_t)b.z; r[7] = (bf16_t)b.w;
    return r;
}

__device__ inline f16x2 pkrtz(float a, float b) {
    return __builtin_bit_cast(f16x2, __builtin_amdgcn_cvt_pkrtz(a, b));
}

// ---------------- kernel A: projections (once per window, unchanged) ----------------
__global__ __launch_bounds__(512) void swa_proj(
    const float* __restrict__ q, const float* __restrict__ k,
    const float* __restrict__ v, const float* __restrict__ w,
    const float* __restrict__ bias,
    f16_t* __restrict__ qpg, f16_t* __restrict__ kpg, f16_t* __restrict__ vpg)
{
    __shared__ __align__(16) f16_t stq[128][72];
    __shared__ __align__(16) f16_t stk[128][72];
    __shared__ __align__(16) f16_t vt[64][136];

    int tid = threadIdx.x, lane = tid & 63, wave = tid >> 6;
    int bid = blockIdx.x;
    int n = bid >> 2, rg = bid & 3;
    int ml = lane & 15, quad = lane >> 4;
    int srow = wave * 16;
    int s0 = rg * 128 + srow;
    int arow = (s0 + ml) * L_DIM + 32 * n + quad * 8;
    const float cs = 0.35355339059327373f * 1.4426950408889634f;

    bf16x8 qa0 = cvt8(q + arow), qa1 = cvt8(q + arow + 32);
    bf16x8 ka0 = cvt8(k + arow), ka1 = cvt8(k + arow + 32);
    bf16x8 va0 = cvt8(v + arow), va1 = cvt8(v + arow + 32);

#pragma unroll
    for (int et = 0; et < 4; ++et) {
        bf16x8 wq0 = cvt8(w + (et * 16 + ml) * 64 + quad * 8);
        bf16x8 wq1 = cvt8(w + (et * 16 + ml) * 64 + 32 + quad * 8);
        bf16x8 wk0 = cvt8(w + (64 + et * 16 + ml) * 64 + quad * 8);
        bf16x8 wk1 = cvt8(w + (64 + et * 16 + ml) * 64 + 32 + quad * 8);
        bf16x8 wv0 = cvt8(w + (128 + et * 16 + ml) * 64 + quad * 8);
        bf16x8 wv1 = cvt8(w + (128 + et * 16 + ml) * 64 + 32 + quad * 8);

        float bq = bias[et * 16 + ml];
        float bk = bias[64 + et * 16 + ml];
        float bv = bias[128 + et * 16 + ml];
        f32x4 qacc = (f32x4){bq, bq, bq, bq};
        f32x4 kacc = (f32x4){bk, bk, bk, bk};
        f32x4 vacc = (f32x4){bv, bv, bv, bv};
        qacc = __builtin_amdgcn_mfma_f32_16x16x32_bf16(qa0, wq0, qacc, 0, 0, 0);
        qacc = __builtin_amdgcn_mfma_f32_16x16x32_bf16(qa1, wq1, qacc, 0, 0, 0);
        kacc = __builtin_amdgcn_mfma_f32_16x16x32_bf16(ka0, wk0, kacc, 0, 0, 0);
        kacc = __builtin_amdgcn_mfma_f32_16x16x32_bf16(ka1, wk1, kacc, 0, 0, 0);
        vacc = __builtin_amdgcn_mfma_f32_16x16x32_bf16(va0, wv0, vacc, 0, 0, 0);
        vacc = __builtin_amdgcn_mfma_f32_16x16x32_bf16(va1, wv1, vacc, 0, 0, 0);

#pragma unroll
        for (int rr = 0; rr < 4; ++rr) {
            int row = srow + quad * 4 + rr;
            stq[row][et * 16 + ml] = (f16_t)(qacc[rr] * cs);
            stk[row][et * 16 + ml] = (f16_t)kacc[rr];
            vt[et * 16 + ml][row]  = (f16_t)vacc[rr];
        }
    }
    __syncthreads();

    {
        const size_t qbase = ((size_t)n * S_DIM + rg * 128) * 64;
#pragma unroll
        for (int c = tid; c < 1024; c += 512) {
            int row = c >> 3, col = (c & 7) * 8;
            *(uint4*)(qpg + qbase + (size_t)row * 64 + col) = *(const uint4*)&stq[row][col];
        }
    }
    {
#pragma unroll
        for (int c = tid; c < 1024; c += 512) {
            int et = c >> 8, cc = c & 255, row = cc >> 1, hf = cc & 1;
            *(uint4*)(kpg + (((size_t)n * 4 + et) * S_DIM + rg * 128 + row) * 16 + hf * 8) =
                *(const uint4*)&stk[row][et * 16 + hf * 8];
        }
    }
    {
#pragma unroll
        for (int c = tid; c < 1024; c += 512) {
            int vr = c >> 4, sc = c & 15;
            *(uint4*)(vpg + (((size_t)n * 4 + (vr >> 4)) * 16 + (vr & 15)) * S_DIM +
                      rg * 128 + sc * 8) = *(const uint4*)&vt[vr][sc * 8];
        }
    }
}

// ---------------- kernel B: attention ----------------
__global__ __launch_bounds__(512, 4) void swa_attn(
    const f16_t* __restrict__ qpg, const f16_t* __restrict__ kpg,
    const f16_t* __restrict__ vpg, const float* __restrict__ wout,
    const float* __restrict__ bout, float* __restrict__ out)
{
    __shared__ __align__(16) f16_t kp_s[S_DIM][18];       // [key][h01*8+d] pad18
    __shared__ __align__(16) f16_t vp_t[16][520];         // [h01*8+d][key]
    __shared__ __align__(16) f16_t qp_t[2][16][68];       // [m][q][e]
    __shared__ __align__(16) f16_t zstub[8];
    __shared__ __align__(16) float wsum_s[2][2][16][4];   // [h&1][m][q][wg]
    __shared__ __align__(16) f16_t ctxslot[2][4][2][16][8]; // [h01][wg][m][q][d]
    __shared__ float  ctx_s[32][68];
    __shared__ bf16_t wo_t[64][66];
    __shared__ float  bo_s[64];

    int tid = threadIdx.x, lane = tid & 63, wave = tid >> 6;
    int wg = wave >> 1, m = wave & 1;
    int bid = blockIdx.x;
    int n = bid >> 4, tile = bid & 15, srow0 = tile * 32;
    int ml = lane & 15, quad = lane >> 4;
    bool hi = lane >= 32;   // K-dim (hd 8..15) pad lanes for QK^T fragments

    float* out_x  = out;
    float* out_aw = out + (size_t)S_DIM * NW * E_DIM;

#pragma unroll
    for (int i = 0; i < 8; ++i) {
        int idx = tid + i * 512;
        wo_t[idx & 63][idx >> 6] = (bf16_t)wout[idx];
    }
    if (tid < 64) bo_s[tid] = bout[tid];
    if (tid < 8)  zstub[tid] = (f16_t)0.f;
    {
        int row = tid >> 4, c = tid & 15;
        f16x4 qv = *(const f16x4*)(qpg + ((size_t)n * S_DIM + srow0 + row) * 64 + c * 4);
        *(f16x4*)&qp_t[row >> 4][row & 15][c * 4] = qv;
    }

    int idx0 = tid, idx1 = tid + 512;
    uint4 ldk0, ldk1, ldv0, ldv1;
    {
        const f16_t* kb = kpg + ((size_t)n * 4 + 0) * S_DIM * 16;
        ldk0 = *(const uint4*)(kb + (idx0 >> 1) * 16 + (idx0 & 1) * 8);
        ldk1 = *(const uint4*)(kb + (idx1 >> 1) * 16 + (idx1 & 1) * 8);
        const f16_t* vb = vpg + ((size_t)n * 4 + 0) * 16 * S_DIM;
        ldv0 = *(const uint4*)(vb + (idx0 >> 6) * S_DIM + (idx0 & 63) * 8);
        ldv1 = *(const uint4*)(vb + (idx1 >> 6) * S_DIM + (idx1 & 63) * 8);
    }

    // aacc[w][c]: attn-weight accum; keys wg*128 + w*32 + 8*quad + (c?4:0) + reg
    f32x4 aacc[4][2];
#pragma unroll
    for (int t = 0; t < 4; ++t) {
        aacc[t][0] = (f32x4){0.f, 0.f, 0.f, 0.f};
        aacc[t][1] = (f32x4){0.f, 0.f, 0.f, 0.f};
    }

    // permuted K row within a 32-key window: C row r <-> key 8*(r>>2)+(r&3)
    int krow = 8 * (ml >> 2) + (ml & 3);

    for (int hp = 0; hp < 4; ++hp) {
        *(uint4*)&kp_s[idx0 >> 1][(idx0 & 1) * 8] = ldk0;
        *(uint4*)&kp_s[idx1 >> 1][(idx1 & 1) * 8] = ldk1;
        *(uint4*)&vp_t[idx0 >> 6][(idx0 & 63) * 8] = ldv0;
        *(uint4*)&vp_t[idx1 >> 6][(idx1 & 63) * 8] = ldv1;
        if (hp < 3) {
            const f16_t* kb = kpg + ((size_t)n * 4 + hp + 1) * S_DIM * 16;
            ldk0 = *(const uint4*)(kb + (idx0 >> 1) * 16 + (idx0 & 1) * 8);
            ldk1 = *(const uint4*)(kb + (idx1 >> 1) * 16 + (idx1 & 1) * 8);
            const f16_t* vb = vpg + ((size_t)n * 4 + hp + 1) * 16 * S_DIM;
            ldv0 = *(const uint4*)(vb + (idx0 >> 6) * S_DIM + (idx0 & 63) * 8);
            ldv1 = *(const uint4*)(vb + (idx1 >> 6) * S_DIM + (idx1 & 63) * 8);
        }
        __syncthreads();   // BAR_stage

        if (hp > 0) {
            int mm = tid >> 8, qq = (tid >> 4) & 15, hh = (tid >> 3) & 1, dd = tid & 7;
            ctx_s[mm * 16 + qq][(2 * (hp - 1) + hh) * 8 + dd] =
                (float)ctxslot[hh][0][mm][qq][dd] + (float)ctxslot[hh][1][mm][qq][dd] +
                (float)ctxslot[hh][2][mm][qq][dd] + (float)ctxslot[hh][3][mm][qq][dd];
        }

#pragma unroll
        for (int h01 = 0; h01 < 2; ++h01) {
            int h = hp * 2 + h01;

            const f16_t* qsrc = hi ? &zstub[0] : &qp_t[m][ml][h * 8 + quad * 4];
            f16x4 Qf = *(const f16x4*)qsrc;
            const f16_t* kbase = hi ? &zstub[0]
                                    : &kp_s[wg * 128 + krow][h01 * 8 + quad * 4];
            int kwstep = hi ? 0 : 32 * 18;   // next 32-key window
            int k4     = hi ? 0 : 4 * 18;    // +4 keys (second half of window)

            // scores: per 32-key window, 2 x16 MFMAs; C row r <-> key 8q+r / 8q+4+r
            f32x4 SC[4][2];
#pragma unroll
            for (int t = 0; t < 4; ++t) {
                f16x4 K1 = *(const f16x4*)(kbase + t * kwstep);
                f16x4 K2 = *(const f16x4*)(kbase + t * kwstep + k4);
                SC[t][0] = __builtin_amdgcn_mfma_f32_16x16x16f16(K1, Qf, (f32x4){0.f,0.f,0.f,0.f}, 0, 0, 0);
                SC[t][1] = __builtin_amdgcn_mfma_f32_16x16x16f16(K2, Qf, (f32x4){0.f,0.f,0.f,0.f}, 0, 0, 0);
            }

            // exp2 (no max pass; log2-domain scores small) + row partial sum
#pragma unroll
            for (int t = 0; t < 4; ++t)
#pragma unroll
                for (int c = 0; c < 2; ++c) {
                    SC[t][c][0] = exp2f(SC[t][c][0]);
                    SC[t][c][1] = exp2f(SC[t][c][1]);
                    SC[t][c][2] = exp2f(SC[t][c][2]);
                    SC[t][c][3] = exp2f(SC[t][c][3]);
                }
            f32x4 sA = ((SC[0][0] + SC[0][1]) + (SC[1][0] + SC[1][1])) +
                       ((SC[2][0] + SC[2][1]) + (SC[3][0] + SC[3][1]));
            float ls = (sA[0] + sA[1]) + (sA[2] + sA[3]);
            ls += __shfl_xor(ls, 16, 64);
            ls += __shfl_xor(ls, 32, 64);
            if (lane < 16) wsum_s[h & 1][m][lane][wg] = ls;

            // PV: x32 MFMA, dense over keys; P already in x32 B-frag order (k=8q+idx)
            const f16_t* vbase = &vp_t[h01 * 8 + (ml & 7)][wg * 128 + quad * 8];
            f32x4 cacc = (f32x4){0.f, 0.f, 0.f, 0.f};
#pragma unroll
            for (int t = 0; t < 4; ++t) {
                f16x8 Af = *(const f16x8*)(vbase + t * 32);
                f16x2 p0 = pkrtz(SC[t][0][0], SC[t][0][1]);
                f16x2 p1 = pkrtz(SC[t][0][2], SC[t][0][3]);
                f16x2 p2 = pkrtz(SC[t][1][0], SC[t][1][1]);
                f16x2 p3 = pkrtz(SC[t][1][2], SC[t][1][3]);
                f16x8 Pf;
                Pf[0] = p0[0]; Pf[1] = p0[1]; Pf[2] = p1[0]; Pf[3] = p1[1];
                Pf[4] = p2[0]; Pf[5] = p2[1]; Pf[6] = p3[0]; Pf[7] = p3[1];
                cacc = __builtin_amdgcn_mfma_f32_16x16x32_f16(Af, Pf, cacc, 0, 0, 0);
            }
            __syncthreads();   // BAR_sum(h)

            f32x4 ws4 = *(const f32x4*)&wsum_s[h & 1][m][ml][0];
            float inv = 1.0f / ((ws4[0] + ws4[1]) + (ws4[2] + ws4[3]));

            float wgt = 0.125f * inv;
            f32x4 wv = (f32x4){wgt, wgt, wgt, wgt};
#pragma unroll
            for (int t = 0; t < 4; ++t) {
                aacc[t][0] = __builtin_elementwise_fma(SC[t][0], wv, aacc[t][0]);
                aacc[t][1] = __builtin_elementwise_fma(SC[t][1], wv, aacc[t][1]);
            }

            cacc = cacc * (f32x4){inv, inv, inv, inv};
            if (lane < 32) {
                f16x4 cw;
                cw[0] = (f16_t)cacc[0]; cw[1] = (f16_t)cacc[1];
                cw[2] = (f16_t)cacc[2]; cw[3] = (f16_t)cacc[3];
                *(f16x4*)&ctxslot[h01][wg][m][ml][quad * 4] = cw;
            }
        }
    }

    __syncthreads();
    {
        int mm = tid >> 8, qq = (tid >> 4) & 15, hh = (tid >> 3) & 1, dd = tid & 7;
        ctx_s[mm * 16 + qq][(6 + hh) * 8 + dd] =
            (float)ctxslot[hh][0][mm][qq][dd] + (float)ctxslot[hh][1][mm][qq][dd] +
            (float)ctxslot[hh][2][mm][qq][dd] + (float)ctxslot[hh][3][mm][qq][dd];
    }

    // attn_weights: keys wg*128 + t*32 + 8*quad + {0..3} and +4
    {
        int row = srow0 + m * 16 + ml;
        float* dst = out_aw + ((size_t)(n * S_DIM + row)) * S_DIM + wg * 128 + quad * 8;
#pragma unroll
        for (int t = 0; t < 4; ++t) {
            *(f32x4*)&dst[t * 32]     = aacc[t][0];
            *(f32x4*)&dst[t * 32 + 4] = aacc[t][1];
        }
    }
    __syncthreads();

    int so = tid >> 4;
    int eb = tid & 15;
    float xacc[4];
#pragma unroll
    for (int kk = 0; kk < 4; ++kk) xacc[kk] = bo_s[eb + 16 * kk];
#pragma unroll
    for (int f = 0; f < 64; ++f) {
        float c = ctx_s[so][f];
#pragma unroll
        for (int kk = 0; kk < 4; ++kk)
            xacc[kk] = fmaf(c, (float)wo_t[f][eb + 16 * kk], xacc[kk]);
    }
    int sg = srow0 + so;
#pragma unroll
    for (int kk = 0; kk < 4; ++kk)
        out_x[((size_t)sg * NW + n) * E_DIM + eb + 16 * kk] = xacc[kk];
}

extern "C" void kernel_launch(void* const* d_in, const int* in_sizes, int n_in,
                              void* d_out, int out_size, void* d_ws, size_t ws_size,
                              hipStream_t stream) {
    const float* q  = (const float*)d_in[0];
    const float* k  = (const float*)d_in[1];
    const float* v  = (const float*)d_in[2];
    const float* w  = (const float*)d_in[3];
    const float* b  = (const float*)d_in[4];
    const float* wo = (const float*)d_in[5];
    const float* bo = (const float*)d_in[6];
    float* out = (float*)d_out;

    // workspace: 3 x 63*512*64 f16 = 12.4MB
    const size_t NP = (size_t)NW * S_DIM * 64;
    f16_t* qpg = (f16_t*)d_ws;
    f16_t* kpg = qpg + NP;
    f16_t* vpg = kpg + NP;

    hipLaunchKernelGGL(swa_proj, dim3(NW * 4), dim3(512), 0, stream,
                       q, k, v, w, b, qpg, kpg, vpg);
    hipLaunchKernelGGL(swa_attn, dim3(NW * 16), dim3(512), 0, stream,
                       qpg, kpg, vpg, wo, bo, out);
}

// Round 12
// 242.070 us; speedup vs baseline: 1.4406x; 1.4406x over previous
//
#include <hip/hip_runtime.h>

// SlidingWindowAttention: S=512, L=2048, WINDOW=64, STRIDE=32 -> NW=63, E=64, H=8, HD=8
// R12: revert swa_attn to __launch_bounds__(512,2) -- third confirmation that
// min-waves=4 makes the allocator split 64V+64A and spill (~100 live > 64V:
// R11 WRITE 72.6->459.6MB, dur 99->273us). KEEP R11's x32 PV + permuted-K QK
// (correctness-proven, absmax 0.0078125): 4 PV MFMAs/head instead of 8, b128 V
// reads. At (512,2) the 256-reg budget holds the live set with zero scratch.
// Known residual: b128 V reads are inherently 4-way banked (32 addrs x 4 banks)
// ~= 1K cyc/block -- noise. aw-mean reg budget (32 f32/lane) pins the wave
// partition; per-head cross-wave sum barrier is structurally irreducible.
#define S_DIM 512
#define L_DIM 2048
#define NW 63
#define E_DIM 64

typedef __bf16 bf16_t;
typedef __bf16 bf16x8 __attribute__((ext_vector_type(8)));
typedef float f32x4 __attribute__((ext_vector_type(4)));
typedef _Float16 f16_t;
typedef _Float16 f16x2 __attribute__((ext_vector_type(2)));
typedef _Float16 f16x4 __attribute__((ext_vector_type(4)));
typedef _Float16 f16x8 __attribute__((ext_vector_type(8)));

// 8 consecutive f32 -> bf16x8 MFMA fragment
__device__ inline bf16x8 cvt8(const float* __restrict__ p) {
    float4 a = *(const float4*)p;
    float4 b = *(const float4*)(p + 4);
    bf16x8 r;
    r[0] = (bf16_t)a.x; r[1] = (bf16_t)a.y; r[2] = (bf16_t)a.z; r[3] = (bf16_t)a.w;
    r[4] = (bf16_t)b.x; r[5] = (bf16_t)b.y; r[6] = (bf16_t)b.z; r[7] = (bf16_t)b.w;
    return r;
}

__device__ inline f16x2 pkrtz(float a, float b) {
    return __builtin_bit_cast(f16x2, __builtin_amdgcn_cvt_pkrtz(a, b));
}

// ---------------- kernel A: projections (once per window, unchanged) ----------------
__global__ __launch_bounds__(512) void swa_proj(
    const float* __restrict__ q, const float* __restrict__ k,
    const float* __restrict__ v, const float* __restrict__ w,
    const float* __restrict__ bias,
    f16_t* __restrict__ qpg, f16_t* __restrict__ kpg, f16_t* __restrict__ vpg)
{
    __shared__ __align__(16) f16_t stq[128][72];
    __shared__ __align__(16) f16_t stk[128][72];
    __shared__ __align__(16) f16_t vt[64][136];

    int tid = threadIdx.x, lane = tid & 63, wave = tid >> 6;
    int bid = blockIdx.x;
    int n = bid >> 2, rg = bid & 3;
    int ml = lane & 15, quad = lane >> 4;
    int srow = wave * 16;
    int s0 = rg * 128 + srow;
    int arow = (s0 + ml) * L_DIM + 32 * n + quad * 8;
    const float cs = 0.35355339059327373f * 1.4426950408889634f;

    bf16x8 qa0 = cvt8(q + arow), qa1 = cvt8(q + arow + 32);
    bf16x8 ka0 = cvt8(k + arow), ka1 = cvt8(k + arow + 32);
    bf16x8 va0 = cvt8(v + arow), va1 = cvt8(v + arow + 32);

#pragma unroll
    for (int et = 0; et < 4; ++et) {
        bf16x8 wq0 = cvt8(w + (et * 16 + ml) * 64 + quad * 8);
        bf16x8 wq1 = cvt8(w + (et * 16 + ml) * 64 + 32 + quad * 8);
        bf16x8 wk0 = cvt8(w + (64 + et * 16 + ml) * 64 + quad * 8);
        bf16x8 wk1 = cvt8(w + (64 + et * 16 + ml) * 64 + 32 + quad * 8);
        bf16x8 wv0 = cvt8(w + (128 + et * 16 + ml) * 64 + quad * 8);
        bf16x8 wv1 = cvt8(w + (128 + et * 16 + ml) * 64 + 32 + quad * 8);

        float bq = bias[et * 16 + ml];
        float bk = bias[64 + et * 16 + ml];
        float bv = bias[128 + et * 16 + ml];
        f32x4 qacc = (f32x4){bq, bq, bq, bq};
        f32x4 kacc = (f32x4){bk, bk, bk, bk};
        f32x4 vacc = (f32x4){bv, bv, bv, bv};
        qacc = __builtin_amdgcn_mfma_f32_16x16x32_bf16(qa0, wq0, qacc, 0, 0, 0);
        qacc = __builtin_amdgcn_mfma_f32_16x16x32_bf16(qa1, wq1, qacc, 0, 0, 0);
        kacc = __builtin_amdgcn_mfma_f32_16x16x32_bf16(ka0, wk0, kacc, 0, 0, 0);
        kacc = __builtin_amdgcn_mfma_f32_16x16x32_bf16(ka1, wk1, kacc, 0, 0, 0);
        vacc = __builtin_amdgcn_mfma_f32_16x16x32_bf16(va0, wv0, vacc, 0, 0, 0);
        vacc = __builtin_amdgcn_mfma_f32_16x16x32_bf16(va1, wv1, vacc, 0, 0, 0);

#pragma unroll
        for (int rr = 0; rr < 4; ++rr) {
            int row = srow + quad * 4 + rr;
            stq[row][et * 16 + ml] = (f16_t)(qacc[rr] * cs);
            stk[row][et * 16 + ml] = (f16_t)kacc[rr];
            vt[et * 16 + ml][row]  = (f16_t)vacc[rr];
        }
    }
    __syncthreads();

    {
        const size_t qbase = ((size_t)n * S_DIM + rg * 128) * 64;
#pragma unroll
        for (int c = tid; c < 1024; c += 512) {
            int row = c >> 3, col = (c & 7) * 8;
            *(uint4*)(qpg + qbase + (size_t)row * 64 + col) = *(const uint4*)&stq[row][col];
        }
    }
    {
#pragma unroll
        for (int c = tid; c < 1024; c += 512) {
            int et = c >> 8, cc = c & 255, row = cc >> 1, hf = cc & 1;
            *(uint4*)(kpg + (((size_t)n * 4 + et) * S_DIM + rg * 128 + row) * 16 + hf * 8) =
                *(const uint4*)&stk[row][et * 16 + hf * 8];
        }
    }
    {
#pragma unroll
        for (int c = tid; c < 1024; c += 512) {
            int vr = c >> 4, sc = c & 15;
            *(uint4*)(vpg + (((size_t)n * 4 + (vr >> 4)) * 16 + (vr & 15)) * S_DIM +
                      rg * 128 + sc * 8) = *(const uint4*)&vt[vr][sc * 8];
        }
    }
}

// ---------------- kernel B: attention ----------------
__global__ __launch_bounds__(512, 2) void swa_attn(
    const f16_t* __restrict__ qpg, const f16_t* __restrict__ kpg,
    const f16_t* __restrict__ vpg, const float* __restrict__ wout,
    const float* __restrict__ bout, float* __restrict__ out)
{
    __shared__ __align__(16) f16_t kp_s[S_DIM][18];       // [key][h01*8+d] pad18
    __shared__ __align__(16) f16_t vp_t[16][520];         // [h01*8+d][key]
    __shared__ __align__(16) f16_t qp_t[2][16][68];       // [m][q][e]
    __shared__ __align__(16) f16_t zstub[8];
    __shared__ __align__(16) float wsum_s[2][2][16][4];   // [h&1][m][q][wg]
    __shared__ __align__(16) f16_t ctxslot[2][4][2][16][8]; // [h01][wg][m][q][d]
    __shared__ float  ctx_s[32][68];
    __shared__ bf16_t wo_t[64][66];
    __shared__ float  bo_s[64];

    int tid = threadIdx.x, lane = tid & 63, wave = tid >> 6;
    int wg = wave >> 1, m = wave & 1;
    int bid = blockIdx.x;
    int n = bid >> 4, tile = bid & 15, srow0 = tile * 32;
    int ml = lane & 15, quad = lane >> 4;
    bool hi = lane >= 32;   // K-dim (hd 8..15) pad lanes for QK^T fragments

    float* out_x  = out;
    float* out_aw = out + (size_t)S_DIM * NW * E_DIM;

#pragma unroll
    for (int i = 0; i < 8; ++i) {
        int idx = tid + i * 512;
        wo_t[idx & 63][idx >> 6] = (bf16_t)wout[idx];
    }
    if (tid < 64) bo_s[tid] = bout[tid];
    if (tid < 8)  zstub[tid] = (f16_t)0.f;
    {
        int row = tid >> 4, c = tid & 15;
        f16x4 qv = *(const f16x4*)(qpg + ((size_t)n * S_DIM + srow0 + row) * 64 + c * 4);
        *(f16x4*)&qp_t[row >> 4][row & 15][c * 4] = qv;
    }

    int idx0 = tid, idx1 = tid + 512;
    uint4 ldk0, ldk1, ldv0, ldv1;
    {
        const f16_t* kb = kpg + ((size_t)n * 4 + 0) * S_DIM * 16;
        ldk0 = *(const uint4*)(kb + (idx0 >> 1) * 16 + (idx0 & 1) * 8);
        ldk1 = *(const uint4*)(kb + (idx1 >> 1) * 16 + (idx1 & 1) * 8);
        const f16_t* vb = vpg + ((size_t)n * 4 + 0) * 16 * S_DIM;
        ldv0 = *(const uint4*)(vb + (idx0 >> 6) * S_DIM + (idx0 & 63) * 8);
        ldv1 = *(const uint4*)(vb + (idx1 >> 6) * S_DIM + (idx1 & 63) * 8);
    }

    // aacc[w][c]: attn-weight accum; keys wg*128 + w*32 + 8*quad + (c?4:0) + reg
    f32x4 aacc[4][2];
#pragma unroll
    for (int t = 0; t < 4; ++t) {
        aacc[t][0] = (f32x4){0.f, 0.f, 0.f, 0.f};
        aacc[t][1] = (f32x4){0.f, 0.f, 0.f, 0.f};
    }

    // permuted K row within a 32-key window: C row r <-> key 8*(r>>2)+(r&3)
    int krow = 8 * (ml >> 2) + (ml & 3);

    for (int hp = 0; hp < 4; ++hp) {
        *(uint4*)&kp_s[idx0 >> 1][(idx0 & 1) * 8] = ldk0;
        *(uint4*)&kp_s[idx1 >> 1][(idx1 & 1) * 8] = ldk1;
        *(uint4*)&vp_t[idx0 >> 6][(idx0 & 63) * 8] = ldv0;
        *(uint4*)&vp_t[idx1 >> 6][(idx1 & 63) * 8] = ldv1;
        if (hp < 3) {
            const f16_t* kb = kpg + ((size_t)n * 4 + hp + 1) * S_DIM * 16;
            ldk0 = *(const uint4*)(kb + (idx0 >> 1) * 16 + (idx0 & 1) * 8);
            ldk1 = *(const uint4*)(kb + (idx1 >> 1) * 16 + (idx1 & 1) * 8);
            const f16_t* vb = vpg + ((size_t)n * 4 + hp + 1) * 16 * S_DIM;
            ldv0 = *(const uint4*)(vb + (idx0 >> 6) * S_DIM + (idx0 & 63) * 8);
            ldv1 = *(const uint4*)(vb + (idx1 >> 6) * S_DIM + (idx1 & 63) * 8);
        }
        __syncthreads();   // BAR_stage

        if (hp > 0) {
            int mm = tid >> 8, qq = (tid >> 4) & 15, hh = (tid >> 3) & 1, dd = tid & 7;
            ctx_s[mm * 16 + qq][(2 * (hp - 1) + hh) * 8 + dd] =
                (float)ctxslot[hh][0][mm][qq][dd] + (float)ctxslot[hh][1][mm][qq][dd] +
                (float)ctxslot[hh][2][mm][qq][dd] + (float)ctxslot[hh][3][mm][qq][dd];
        }

#pragma unroll
        for (int h01 = 0; h01 < 2; ++h01) {
            int h = hp * 2 + h01;

            const f16_t* qsrc = hi ? &zstub[0] : &qp_t[m][ml][h * 8 + quad * 4];
            f16x4 Qf = *(const f16x4*)qsrc;
            const f16_t* kbase = hi ? &zstub[0]
                                    : &kp_s[wg * 128 + krow][h01 * 8 + quad * 4];
            int kwstep = hi ? 0 : 32 * 18;   // next 32-key window
            int k4     = hi ? 0 : 4 * 18;    // +4 keys (second half of window)

            // scores: per 32-key window, 2 x16 MFMAs; C row r <-> key 8q+r / 8q+4+r
            f32x4 SC[4][2];
#pragma unroll
            for (int t = 0; t < 4; ++t) {
                f16x4 K1 = *(const f16x4*)(kbase + t * kwstep);
                f16x4 K2 = *(const f16x4*)(kbase + t * kwstep + k4);
                SC[t][0] = __builtin_amdgcn_mfma_f32_16x16x16f16(K1, Qf, (f32x4){0.f,0.f,0.f,0.f}, 0, 0, 0);
                SC[t][1] = __builtin_amdgcn_mfma_f32_16x16x16f16(K2, Qf, (f32x4){0.f,0.f,0.f,0.f}, 0, 0, 0);
            }

            // exp2 (no max pass; log2-domain scores small) + row partial sum
#pragma unroll
            for (int t = 0; t < 4; ++t)
#pragma unroll
                for (int c = 0; c < 2; ++c) {
                    SC[t][c][0] = exp2f(SC[t][c][0]);
                    SC[t][c][1] = exp2f(SC[t][c][1]);
                    SC[t][c][2] = exp2f(SC[t][c][2]);
                    SC[t][c][3] = exp2f(SC[t][c][3]);
                }
            f32x4 sA = ((SC[0][0] + SC[0][1]) + (SC[1][0] + SC[1][1])) +
                       ((SC[2][0] + SC[2][1]) + (SC[3][0] + SC[3][1]));
            float ls = (sA[0] + sA[1]) + (sA[2] + sA[3]);
            ls += __shfl_xor(ls, 16, 64);
            ls += __shfl_xor(ls, 32, 64);
            if (lane < 16) wsum_s[h & 1][m][lane][wg] = ls;

            // PV: x32 MFMA, dense over keys; P already in x32 B-frag order (k=8q+idx)
            const f16_t* vbase = &vp_t[h01 * 8 + (ml & 7)][wg * 128 + quad * 8];
            f32x4 cacc = (f32x4){0.f, 0.f, 0.f, 0.f};
#pragma unroll
            for (int t = 0; t < 4; ++t) {
                f16x8 Af = *(const f16x8*)(vbase + t * 32);
                f16x2 p0 = pkrtz(SC[t][0][0], SC[t][0][1]);
                f16x2 p1 = pkrtz(SC[t][0][2], SC[t][0][3]);
                f16x2 p2 = pkrtz(SC[t][1][0], SC[t][1][1]);
                f16x2 p3 = pkrtz(SC[t][1][2], SC[t][1][3]);
                f16x8 Pf;
                Pf[0] = p0[0]; Pf[1] = p0[1]; Pf[2] = p1[0]; Pf[3] = p1[1];
                Pf[4] = p2[0]; Pf[5] = p2[1]; Pf[6] = p3[0]; Pf[7] = p3[1];
                cacc = __builtin_amdgcn_mfma_f32_16x16x32_f16(Af, Pf, cacc, 0, 0, 0);
            }
            __syncthreads();   // BAR_sum(h)

            f32x4 ws4 = *(const f32x4*)&wsum_s[h & 1][m][ml][0];
            float inv = 1.0f / ((ws4[0] + ws4[1]) + (ws4[2] + ws4[3]));

            float wgt = 0.125f * inv;
            f32x4 wv = (f32x4){wgt, wgt, wgt, wgt};
#pragma unroll
            for (int t = 0; t < 4; ++t) {
                aacc[t][0] = __builtin_elementwise_fma(SC[t][0], wv, aacc[t][0]);
                aacc[t][1] = __builtin_elementwise_fma(SC[t][1], wv, aacc[t][1]);
            }

            cacc = cacc * (f32x4){inv, inv, inv, inv};
            if (lane < 32) {
                f16x4 cw;
                cw[0] = (f16_t)cacc[0]; cw[1] = (f16_t)cacc[1];
                cw[2] = (f16_t)cacc[2]; cw[3] = (f16_t)cacc[3];
                *(f16x4*)&ctxslot[h01][wg][m][ml][quad * 4] = cw;
            }
        }
    }

    __syncthreads();
    {
        int mm = tid >> 8, qq = (tid >> 4) & 15, hh = (tid >> 3) & 1, dd = tid & 7;
        ctx_s[mm * 16 + qq][(6 + hh) * 8 + dd] =
            (float)ctxslot[hh][0][mm][qq][dd] + (float)ctxslot[hh][1][mm][qq][dd] +
            (float)ctxslot[hh][2][mm][qq][dd] + (float)ctxslot[hh][3][mm][qq][dd];
    }

    // attn_weights: keys wg*128 + t*32 + 8*quad + {0..3} and +4
    {
        int row = srow0 + m * 16 + ml;
        float* dst = out_aw + ((size_t)(n * S_DIM + row)) * S_DIM + wg * 128 + quad * 8;
#pragma unroll
        for (int t = 0; t < 4; ++t) {
            *(f32x4*)&dst[t * 32]     = aacc[t][0];
            *(f32x4*)&dst[t * 32 + 4] = aacc[t][1];
        }
    }
    __syncthreads();

    int so = tid >> 4;
    int eb = tid & 15;
    float xacc[4];
#pragma unroll
    for (int kk = 0; kk < 4; ++kk) xacc[kk] = bo_s[eb + 16 * kk];
#pragma unroll
    for (int f = 0; f < 64; ++f) {
        float c = ctx_s[so][f];
#pragma unroll
        for (int kk = 0; kk < 4; ++kk)
            xacc[kk] = fmaf(c, (float)wo_t[f][eb + 16 * kk], xacc[kk]);
    }
    int sg = srow0 + so;
#pragma unroll
    for (int kk = 0; kk < 4; ++kk)
        out_x[((size_t)sg * NW + n) * E_DIM + eb + 16 * kk] = xacc[kk];
}

extern "C" void kernel_launch(void* const* d_in, const int* in_sizes, int n_in,
                              void* d_out, int out_size, void* d_ws, size_t ws_size,
                              hipStream_t stream) {
    const float* q  = (const float*)d_in[0];
    const float* k  = (const float*)d_in[1];
    const float* v  = (const float*)d_in[2];
    const float* w  = (const float*)d_in[3];
    const float* b  = (const float*)d_in[4];
    const float* wo = (const float*)d_in[5];
    const float* bo = (const float*)d_in[6];
    float* out = (float*)d_out;

    // workspace: 3 x 63*512*64 f16 = 12.4MB
    const size_t NP = (size_t)NW * S_DIM * 64;
    f16_t* qpg = (f16_t*)d_ws;
    f16_t* kpg = qpg + NP;
    f16_t* vpg = kpg + NP;

    hipLaunchKernelGGL(swa_proj, dim3(NW * 4), dim3(512), 0, stream,
                       q, k, v, w, b, qpg, kpg, vpg);
    hipLaunchKernelGGL(swa_attn, dim3(NW * 16), dim3(512), 0, stream,
                       qpg, kpg, vpg, wo, bo, out);
}